// Round 6
// baseline (332.318 us; speedup 1.0000x reference)
//
#include <hip/hip_runtime.h>
#include <hip/hip_bf16.h>

// Capsule routing without materializing hat (B,C,N,D):
//   b[c,n] = x[n,:]·w~[c,:],  w~[c,k] = sum_d o[c,d] W[k,c*16+d]
//   y[c,k] = sum_n softmax_c(b)[c,n] x[n,k],  o = squash(y[c,:]·W_c)
// 4 dispatches: prep (x->bf16 swizzled + colsum partials),
// pass x2 (in-block o/w~ prologue + score/softmax/y-partials), out.

#define SEQ 2048
#define KD  128

typedef __attribute__((ext_vector_type(8))) short bf16x8;
typedef __attribute__((ext_vector_type(4))) float f32x4;

__device__ __forceinline__ short f2bf(float f) {
  unsigned u = __float_as_uint(f);
  u = u + 0x7fffu + ((u >> 16) & 1u);   // RNE
  return (short)(u >> 16);
}
// lx swizzle: rows 8/16/24 apart land in distinct 32B windows (GEMM2 gather 2-way)
__device__ __forceinline__ int swz(int row) {
  return ((row & 7) << 4) ^ ((row & 24) << 2);
}

// ---- prep: x fp32 -> bf16 pre-swizzled 128-row chunks + colsum partial ----
__global__ __launch_bounds__(256) void prep_k(const float* __restrict__ x,
                                              short* __restrict__ xs,
                                              float* __restrict__ Sp) {
  int blk = blockIdx.x;                 // 2048 chunks of 128 rows
  int t = threadIdx.x, oct = t & 15, rsub = t >> 4;
  size_t row0 = (size_t)blk * 128;
  char* dst = (char*)xs + (size_t)blk * 32768;
  float sac[8] = {0.f,0.f,0.f,0.f,0.f,0.f,0.f,0.f};
  #pragma unroll
  for (int sub = 0; sub < 8; ++sub) {
    int r = sub * 16 + rsub;
    const float* gp = x + (row0 + r) * KD + oct * 8;
    float4 f0 = *(const float4*)gp, f1 = *(const float4*)(gp + 4);
    bf16x8 v; short* vp = (short*)&v;
    vp[0] = f2bf(f0.x); vp[1] = f2bf(f0.y); vp[2] = f2bf(f0.z); vp[3] = f2bf(f0.w);
    vp[4] = f2bf(f1.x); vp[5] = f2bf(f1.y); vp[6] = f2bf(f1.z); vp[7] = f2bf(f1.w);
    sac[0] += f0.x; sac[1] += f0.y; sac[2] += f0.z; sac[3] += f0.w;
    sac[4] += f1.x; sac[5] += f1.y; sac[6] += f1.z; sac[7] += f1.w;
    *(bf16x8*)(dst + ((r * 256 + oct * 16) ^ swz(r))) = v;
  }
  __shared__ float red[2048];           // [rsub][k]
  float4* rp = (float4*)&red[rsub * 128 + oct * 8];
  rp[0] = make_float4(sac[0], sac[1], sac[2], sac[3]);
  rp[1] = make_float4(sac[4], sac[5], sac[6], sac[7]);
  __syncthreads();
  if (t < 128) {
    float s = 0.f;
    #pragma unroll
    for (int i = 0; i < 16; ++i) s += red[i * 128 + t];
    Sp[blk * KD + t] = s;               // plain partial store, no atomics
  }
}

// ---- fused pass: prologue computes o,w~ in-block; main loop = scores ->
// softmax(32) -> y-partial GEMM. 4 blocks/batch, 256 thr. ----
__global__ __launch_bounds__(256, 2) void pass_k(const short* __restrict__ xs,
                                                 const float* __restrict__ W,
                                                 const float* __restrict__ Sp,
                                                 const float* __restrict__ ypin,
                                                 float* __restrict__ yout,
                                                 int iter0) {
  __shared__ char ldsbuf[49152];
  char* lx  = ldsbuf;                   // 32KB: x chunk 128 rows x 256B, swz
  char* lw  = ldsbuf + 32768;           // 8KB:  w~ 32 x 128 bf16
  char* lcn = ldsbuf + 40960;           // 8KB:  cn^T 32 x 128 bf16
  float* yv   = (float*)ldsbuf;         // prologue: y (32x128) f32, 16KB
  float* sarr = (float*)(ldsbuf + 16384); // prologue: s / Ssum, 2KB
  float* olds = (float*)(ldsbuf + 18432); // prologue: o (32x16), 2KB
  float* yred = (float*)ldsbuf;         // epilogue alias

  int b = blockIdx.x >> 2;
  int t = threadIdx.x;
  int wv = t >> 6, lane = t & 63, l15 = lane & 15, lg = lane >> 4;

  // ---------- prologue: yv -> s -> o -> w~ (redundant per block) ----------
  if (iter0) {
    if (t < 128) {                      // Ssum over the batch's 16 chunk partials
      float s = 0.f;
      #pragma unroll
      for (int j = 0; j < 16; ++j) s += Sp[(b * 16 + j) * KD + t];
      sarr[t] = s * (1.f / 32.f);
    }
    __syncthreads();
    #pragma unroll
    for (int i = 0; i < 16; ++i) { int idx = i * 256 + t; yv[idx] = sarr[idx & 127]; }
  } else {
    const float* y0 = ypin + (size_t)b * 4 * 4096;
    #pragma unroll
    for (int i = 0; i < 16; ++i) {
      int idx = i * 256 + t;
      yv[idx] = y0[idx] + y0[4096 + idx] + y0[8192 + idx] + y0[12288 + idx];
    }
  }
  __syncthreads();
  float sreg[2];
  #pragma unroll
  for (int h = 0; h < 2; ++h) {         // s[c,d] = y[c,:]·W[:,c*16+d]
    int cd = h * 256 + t, c = cd >> 4, d = cd & 15;
    float acc = 0.f;
    #pragma unroll 8
    for (int k = 0; k < KD; ++k) acc += yv[c * KD + k] * W[k * 512 + c * 16 + d];
    sreg[h] = acc;
  }
  __syncthreads();                      // yv no longer needed
  sarr[t] = sreg[0]; sarr[256 + t] = sreg[1];
  __syncthreads();
  #pragma unroll
  for (int h = 0; h < 2; ++h) {         // squash per capsule
    int cd = h * 256 + t, c = cd >> 4;
    float s2 = 1e-7f;
    #pragma unroll
    for (int dd = 0; dd < 16; ++dd) { float v = sarr[c * 16 + dd]; s2 += v * v; }
    olds[cd] = (sqrtf(s2) / (0.5f + s2)) * sreg[h];
  }
  __syncthreads();
  #pragma unroll
  for (int i = 0; i < 16; ++i) {        // w~[c,k] -> lw bf16 swizzled
    int idx = i * 256 + t, c = idx >> 7, k = idx & 127;
    float acc = 0.f;
    #pragma unroll
    for (int dd = 0; dd < 16; ++dd) acc += olds[c * 16 + dd] * W[k * 512 + c * 16 + dd];
    *(short*)(lw + ((c * 256 + k * 2) ^ ((c & 7) << 4))) = f2bf(acc);
  }
  __syncthreads();

  // ---------- main loop ----------
  f32x4 zz = {0.f, 0.f, 0.f, 0.f};
  f32x4 yacc[2][8];
  #pragma unroll
  for (int i = 0; i < 2; ++i)
    #pragma unroll
    for (int j = 0; j < 8; ++j) yacc[i][j] = zz;

  for (int chunk = 0; chunk < 4; ++chunk) {
    {   // stage pre-swizzled bf16 chunk: pure 16B copies
      const char* gs = (const char*)xs + ((size_t)blockIdx.x * 4 + chunk) * 32768;
      #pragma unroll
      for (int sub = 0; sub < 8; ++sub) {
        int off = sub * 4096 + t * 16;
        *(bf16x8*)(lx + off) = *(const bf16x8*)(gs + off);
      }
    }
    __syncthreads();

    // GEMM1: scores; wave wv owns rows [wv*32, wv*32+32)
    f32x4 sc[2][2];
    sc[0][0] = zz; sc[0][1] = zz; sc[1][0] = zz; sc[1][1] = zz;
    #pragma unroll
    for (int ks = 0; ks < 4; ++ks) {
      bf16x8 a[2], bw[2];
      #pragma unroll
      for (int mi = 0; mi < 2; ++mi) {
        int row = wv * 32 + mi * 16 + l15;
        a[mi] = *(const bf16x8*)(lx + ((row * 256 + ks * 64 + lg * 16) ^ swz(row)));
      }
      #pragma unroll
      for (int ct = 0; ct < 2; ++ct) {
        int cc = ct * 16 + l15;
        bw[ct] = *(const bf16x8*)(lw + ((cc * 256 + ks * 64 + lg * 16) ^ ((cc & 7) << 4)));
      }
      #pragma unroll
      for (int mi = 0; mi < 2; ++mi)
        #pragma unroll
        for (int ct = 0; ct < 2; ++ct)
          sc[mi][ct] = __builtin_amdgcn_mfma_f32_16x16x32_bf16(a[mi], bw[ct], sc[mi][ct], 0, 0, 0);
    }

    // softmax over 32 capsules per row; write cn^T to lcn
    #pragma unroll
    for (int mi = 0; mi < 2; ++mi) {
      #pragma unroll
      for (int r = 0; r < 4; ++r) {
        float v0 = sc[mi][0][r], v1 = sc[mi][1][r];
        float mx = fmaxf(v0, v1);
        mx = fmaxf(mx, __shfl_xor(mx, 1));
        mx = fmaxf(mx, __shfl_xor(mx, 2));
        mx = fmaxf(mx, __shfl_xor(mx, 4));
        mx = fmaxf(mx, __shfl_xor(mx, 8));
        float e0 = __expf(v0 - mx), e1 = __expf(v1 - mx);
        float sm = e0 + e1;
        sm += __shfl_xor(sm, 1); sm += __shfl_xor(sm, 2);
        sm += __shfl_xor(sm, 4); sm += __shfl_xor(sm, 8);
        float inv = 1.f / sm;
        int row = wv * 32 + mi * 16 + lg * 4 + r;
        int c0 = l15, c1 = 16 + l15;
        *(short*)(lcn + ((c0 * 256 + row * 2) ^ ((c0 & 7) << 4))) = f2bf(e0 * inv);
        *(short*)(lcn + ((c1 * 256 + row * 2) ^ ((c1 & 7) << 4))) = f2bf(e1 * inv);
      }
    }
    __syncthreads();

    // GEMM2: y += cn^T @ x; wave wv contracts rows [wv*32, wv*32+32)
    {
      bf16x8 a2[2];
      #pragma unroll
      for (int m2 = 0; m2 < 2; ++m2) {
        int cc = m2 * 16 + l15;
        a2[m2] = *(const bf16x8*)(lcn + ((cc * 256 + wv * 64 + lg * 16) ^ ((cc & 7) << 4)));
      }
      #pragma unroll
      for (int nt = 0; nt < 8; ++nt) {
        bf16x8 bx;
        short* bp = (short*)&bx;
        int col = nt * 16 + l15;
        int rbase = wv * 32 + lg * 8;
        #pragma unroll
        for (int j = 0; j < 8; ++j) {
          int row = rbase + j;
          bp[j] = *(const short*)(lx + ((row * 256 + col * 2) ^ swz(row)));
        }
        yacc[0][nt] = __builtin_amdgcn_mfma_f32_16x16x32_bf16(a2[0], bx, yacc[0][nt], 0, 0, 0);
        yacc[1][nt] = __builtin_amdgcn_mfma_f32_16x16x32_bf16(a2[1], bx, yacc[1][nt], 0, 0, 0);
      }
    }
    __syncthreads();
  }

  // reduce 4 waves' partials in LDS (alias over lx), plain store
  #pragma unroll 1
  for (int round = 0; round < 4; ++round) {
    if (wv == round) {
      #pragma unroll
      for (int m2 = 0; m2 < 2; ++m2)
        #pragma unroll
        for (int nt = 0; nt < 8; ++nt)
          #pragma unroll
          for (int r = 0; r < 4; ++r) {
            int cc = m2 * 16 + lg * 4 + r;   // C/D: col=l15, row=lg*4+r
            int kk = nt * 16 + l15;
            if (round == 0) yred[cc * 128 + kk]  = yacc[m2][nt][r];
            else            yred[cc * 128 + kk] += yacc[m2][nt][r];
          }
    }
    __syncthreads();
  }
  float* yo = yout + (size_t)blockIdx.x * 4096;
  #pragma unroll
  for (int i = 0; i < 16; ++i) yo[i * 256 + t] = yred[i * 256 + t];
}

// ---- out: o2 = squash(y2·W_c) from y2 partials; grid (128b x 32c) x 64 ----
__global__ __launch_bounds__(64) void out_k(const float* __restrict__ W,
                                            const float* __restrict__ yp,
                                            float* __restrict__ out) {
  int b = blockIdx.x >> 5, c = blockIdx.x & 31;
  int l = threadIdx.x, d = l & 15, kg = l >> 4;
  const float* Wc = W + c * 16;
  const float* y0 = yp + (size_t)b * 4 * 4096 + c * KD;
  float s = 0.f;
  #pragma unroll 8
  for (int i = 0; i < 32; ++i) {
    int k = kg * 32 + i;
    float yvv = y0[k] + y0[4096 + k] + y0[8192 + k] + y0[12288 + k];
    s += yvv * Wc[k * 512 + d];
  }
  s += __shfl_xor(s, 16); s += __shfl_xor(s, 32);
  float s2 = s * s;
  s2 += __shfl_xor(s2, 1); s2 += __shfl_xor(s2, 2);
  s2 += __shfl_xor(s2, 4); s2 += __shfl_xor(s2, 8);
  s2 += 1e-7f;
  float o = (sqrtf(s2) / (0.5f + s2)) * s;
  if (l < 16) out[(size_t)b * 512 + c * 16 + l] = o;
}

extern "C" void kernel_launch(void* const* d_in, const int* in_sizes, int n_in,
                              void* d_out, int out_size, void* d_ws, size_t ws_size,
                              hipStream_t stream) {
  const float* x = (const float*)d_in[0];   // (128, 2048, 128) fp32
  const float* W = (const float*)d_in[1];   // (128, 512) fp32
  float* out = (float*)d_out;               // (128, 32, 16) fp32
  char* ws = (char*)d_ws;
  // ws: [Sp 1MB][y1 8MB][y2 8MB][xs 64MB] = 81MB
  float* Sp = (float*)ws;
  float* y1 = (float*)(ws + (1u << 20));
  float* y2 = (float*)(ws + 9u * (1u << 20));
  short* xs = (short*)(ws + 17u * (1u << 20));

  prep_k<<<dim3(2048), dim3(256), 0, stream>>>(x, xs, Sp);
  pass_k<<<dim3(512), dim3(256), 0, stream>>>(xs, W, Sp, nullptr, y1, 1);
  pass_k<<<dim3(512), dim3(256), 0, stream>>>(xs, W, nullptr, y1, y2, 0);
  out_k <<<dim3(4096), dim3(64), 0, stream>>>(W, y2, out);
}